// Round 1
// 569.552 us; speedup vs baseline: 1.0386x; 1.0386x over previous
//
#include <hip/hip_runtime.h>
#include <hip/hip_bf16.h>
#include <stdint.h>

// Problem: LuongConcatAttention (additive attention), fp32 inputs.
//   dec (32,1024) f32; enc (32,2048,1024) f32; W_a (1024,2048) f32; v (1024) f32
//   out alpha (32,2048) f32 = softmax_s( sum_e tanh(decproj[b,e]+encproj[b,s,e]) * v[e] )
// Round 5: pre-convert enc/We to bf16 once (kills 8x/512x redundant VALU pack),
// GEMM becomes m97-structure: global_load_lds width-16 staging + XOR-swizzled
// source/read (rule 21) + 2-barrier K-loop. bf16 RNE numerics unchanged.

typedef __bf16 bf16x8 __attribute__((ext_vector_type(8)));
typedef __bf16 bf16x2 __attribute__((ext_vector_type(2)));
typedef float floatx4 __attribute__((ext_vector_type(4)));
typedef unsigned short ushort_t;

#define M_TOT 65536
#define D_DIM 1024
#define WA_LD 2048
#define S_DIM 2048

__device__ __forceinline__ unsigned int pack2(float a, float b) {
#if __has_builtin(__builtin_amdgcn_cvt_pk_bf16_f32)
    bf16x2 p = __builtin_amdgcn_cvt_pk_bf16_f32(a, b);
    return __builtin_bit_cast(unsigned int, p);
#else
    unsigned int ua = __float_as_uint(a), ub = __float_as_uint(b);
    ua += 0x7fffu + ((ua >> 16) & 1u);     // RNE (inputs finite)
    ub += 0x7fffu + ((ub >> 16) & 1u);
    return __builtin_amdgcn_perm(ub, ua, 0x07060302);  // {ub.hi16, ua.hi16}
#endif
}

// async global->LDS, 16B per lane; LDS dest = wave-uniform base + lane*16
__device__ __forceinline__ void gl16(const ushort_t* g, ushort_t* l) {
    __builtin_amdgcn_global_load_lds(
        (const __attribute__((address_space(1))) unsigned int*)g,
        (__attribute__((address_space(3))) unsigned int*)l,
        16, 0, 0);
}

// ---------------- kernel 0a: We (W_a[:,1024:]) -> bf16 [1024][1024] ----------------
__global__ __launch_bounds__(256) void convertW_kernel(
    const float* __restrict__ Wa, ushort_t* __restrict__ Web)
{
    const int e = blockIdx.x;
    const int k = threadIdx.x * 4;
    float4 wv = *(const float4*)(Wa + (size_t)e * WA_LD + D_DIM + k);
    uint2 pk = { pack2(wv.x, wv.y), pack2(wv.z, wv.w) };
    *(uint2*)(Web + (size_t)e * D_DIM + k) = pk;
}

// ---------------- kernel 0b: enc -> bf16, 67.1M elements, BW-bound ----------------
__global__ __launch_bounds__(256) void convert_enc_kernel(
    const float* __restrict__ in, ushort_t* __restrict__ out)
{
    size_t i = ((size_t)blockIdx.x * 256 + threadIdx.x) * 8;
    const size_t stride = (size_t)4096 * 256 * 8;
    for (int it = 0; it < 8; ++it, i += stride) {
        float4 a = *(const float4*)(in + i);
        float4 b = *(const float4*)(in + i + 4);
        uint4 pk = { pack2(a.x, a.y), pack2(a.z, a.w), pack2(b.x, b.y), pack2(b.z, b.w) };
        *(uint4*)(out + i) = pk;
    }
}

// ---------------- kernel 1: dec_proj[b][e] = sum_k dec[b,k] * W_a[e,k] ----------------
__global__ __launch_bounds__(256) void decproj_kernel(
    const float* __restrict__ dec,
    const float* __restrict__ Wa,
    float* __restrict__ dp)
{
    const int b    = blockIdx.y;
    const int wave = threadIdx.x >> 6;
    const int lane = threadIdx.x & 63;
    const int e    = blockIdx.x * 4 + wave;

    __shared__ float s_d[1024];
    for (int t = threadIdx.x; t < 1024; t += 256)
        s_d[t] = dec[b * 1024 + t];
    __syncthreads();

    const float* wrow = Wa + (size_t)e * WA_LD;   // Wd = W_a[:, :1024]
    float sum = 0.f;
    #pragma unroll
    for (int k0 = 0; k0 < 1024; k0 += 256) {
        float4 w = *(const float4*)(wrow + k0 + lane * 4);
        float4 d = *(const float4*)(&s_d[k0 + lane * 4]);
        sum += w.x * d.x + w.y * d.y + w.z * d.z + w.w * d.w;
    }
    #pragma unroll
    for (int msk = 1; msk < 64; msk <<= 1)
        sum += __shfl_xor(sum, msk, 64);
    if (lane == 0)
        dp[b * 1024 + e] = sum;
}

// ---------------- kernel 2: bf16 GEMM (enc @ We^T) + tanh + v-dot -> partial ----------
// m97 structure: 128x128x32 tile, 256 thr, global_load_lds w=16, 2 barriers/K-step.
// XOR swizzle f(r)=(r&3)^((r>>2)&1): source fetches slot (l&3)^f, reads slot q^f
// -> quarter-wave ds_read_b128 hits 8 distinct bank-quads (2-way aliasing = free).
__global__ __launch_bounds__(256) void gemm_bf16_kernel(
    const ushort_t* __restrict__ A,      // enc bf16 [65536][1024]
    const ushort_t* __restrict__ Bw,     // We  bf16 [1024][1024]
    const float* __restrict__ v,
    const float* __restrict__ dp,
    float* __restrict__ partial)         // [8][65536]
{
    __shared__ ushort_t As[128 * 32];
    __shared__ ushort_t Bs[128 * 32];
    __shared__ float s_dec[128], s_v[128], s_score[128];

    const int tid  = threadIdx.x;
    const int lane = tid & 63;
    const int w    = tid >> 6;
    const int wm   = w >> 1;     // 0..1
    const int wn   = w & 1;      // 0..1
    const int r16  = lane & 15;
    const int q    = lane >> 4;

    // XCD swizzle: 8 n-blocks sharing one A-panel keep flat%8 fixed -> same XCD L2.
    const int flat    = blockIdx.y * 8 + blockIdx.x;
    const int n_block = (flat >> 3) & 7;
    const int m_block = (flat & 7) | ((flat >> 6) << 3);
    const int b_idx   = m_block >> 4;            // 2048/128 = 16 m-tiles per batch row

    if (tid < 128) {
        s_dec[tid] = dp[b_idx * 1024 + n_block * 128 + tid];
        s_v[tid]   = v[n_block * 128 + tid];
    }

    // ---- staging addressing: linear LDS dest, pre-swizzled global source ----
    const int sr = (w << 4) + (lane >> 2);          // row 0..63 within half-tile (f(r+64)==f(r))
    const int fS = (sr & 3) ^ ((sr >> 2) & 1);
    const int sg = ((lane & 3) ^ fS) << 3;          // logical k-slot fetched (elements)
    const ushort_t* Ag = A  + (size_t)(m_block * 128 + sr) * D_DIM + sg;
    const ushort_t* Bg = Bw + (size_t)(n_block * 128 + sr) * D_DIM + sg;
    ushort_t* AsW0 = &As[(w << 4) * 32];            // wave-uniform LDS bases
    ushort_t* AsW1 = &As[(64 + (w << 4)) * 32];
    ushort_t* BsW0 = &Bs[(w << 4) * 32];
    ushort_t* BsW1 = &Bs[(64 + (w << 4)) * 32];

    // ---- fragment read addresses (swizzled, fixed across K since single-buffered) ----
    const int fR = (r16 & 3) ^ ((r16 >> 2) & 1);    // f(wm*64+i*16+r16) == f(r16)
    const int sl = (q ^ fR) << 3;
    const ushort_t* pa[4];
    const ushort_t* pb[4];
    #pragma unroll
    for (int i = 0; i < 4; ++i) {
        pa[i] = &As[(wm * 64 + i * 16 + r16) * 32 + sl];
        pb[i] = &Bs[(wn * 64 + i * 16 + r16) * 32 + sl];
    }

    floatx4 acc[4][4] = {};

    for (int t = 0; t < 32; ++t) {
        const int k0 = t * 32;
        __syncthreads();                       // all waves done reading previous tile
        gl16(Ag + k0,              AsW0);
        gl16(Ag + k0 + 64 * D_DIM, AsW1);
        gl16(Bg + k0,              BsW0);
        gl16(Bg + k0 + 64 * D_DIM, BsW1);
        __syncthreads();                       // vmcnt(0) drain -> tile visible

        bf16x8 af[4], bfr[4];
        #pragma unroll
        for (int i = 0; i < 4; ++i) af[i]  = *(const bf16x8*)pa[i];
        #pragma unroll
        for (int j = 0; j < 4; ++j) bfr[j] = *(const bf16x8*)pb[j];
        #pragma unroll
        for (int i = 0; i < 4; ++i)
            #pragma unroll
            for (int j = 0; j < 4; ++j)
                acc[i][j] = __builtin_amdgcn_mfma_f32_16x16x32_bf16(af[i], bfr[j], acc[i][j], 0, 0, 0);
    }

    // ---- epilogue: h = tanh(acc + dec), p[m] += h * v[n]; reduce over n ----
    float p[4][4] = {};
    #pragma unroll
    for (int j = 0; j < 4; ++j) {
        const int nl = wn * 64 + j * 16 + r16;    // C/D: col = lane&15 -> n
        const float dd = s_dec[nl];
        const float vv = s_v[nl];
        #pragma unroll
        for (int i = 0; i < 4; ++i) {
            #pragma unroll
            for (int r = 0; r < 4; ++r) {         // C/D: row = q*4+r -> m
                float x = acc[i][j][r] + dd;
                if (!(x > -8.f)) x = -8.f;        // NaN-proof clamp
                if (x > 8.f)     x = 8.f;
                float e2 = __expf(2.f * x);
                float h  = 1.f - 2.f * __builtin_amdgcn_rcpf(e2 + 1.f);
                p[i][r] += h * vv;
            }
        }
    }
    #pragma unroll
    for (int msk = 1; msk < 16; msk <<= 1) {
        #pragma unroll
        for (int i = 0; i < 4; ++i)
            #pragma unroll
            for (int r = 0; r < 4; ++r)
                p[i][r] += __shfl_xor(p[i][r], msk, 64);
    }
    __syncthreads();
    if (wn == 0 && r16 == 0) {
        #pragma unroll
        for (int i = 0; i < 4; ++i)
            #pragma unroll
            for (int r = 0; r < 4; ++r)
                s_score[wm * 64 + i * 16 + q * 4 + r] = p[i][r];
    }
    __syncthreads();
    if (wn == 1 && r16 == 0) {
        #pragma unroll
        for (int i = 0; i < 4; ++i)
            #pragma unroll
            for (int r = 0; r < 4; ++r)
                s_score[wm * 64 + i * 16 + q * 4 + r] += p[i][r];
    }
    __syncthreads();
    if (tid < 128)
        partial[(size_t)n_block * M_TOT + m_block * 128 + tid] = s_score[tid];
}

// ---------------- fallback GEMM (fp32 in-kernel pack) if workspace too small ----------
__global__ __launch_bounds__(256) void fused_gemm_fp32_kernel(
    const float* __restrict__ enc,
    const float* __restrict__ Wa,
    const float* __restrict__ v,
    const float* __restrict__ dp,
    float* __restrict__ partial)
{
    __shared__ unsigned short As[128 * 32];
    __shared__ unsigned short Bs[128 * 32];
    __shared__ float s_dec[128];
    __shared__ float s_v[128];
    __shared__ float s_score[128];

    const int tid  = threadIdx.x;
    const int lane = tid & 63;
    const int wave = tid >> 6;
    const int wm   = wave >> 1;
    const int wn   = wave & 1;

    const int flat    = blockIdx.y * 8 + blockIdx.x;
    const int n_block = (flat >> 3) & 7;
    const int m_block = (flat & 7) | ((flat >> 6) << 3);
    const int b_idx   = m_block >> 4;

    if (tid < 128) {
        s_dec[tid] = dp[b_idx * 1024 + n_block * 128 + tid];
        s_v[tid]   = v[n_block * 128 + tid];
    }

    const int r0  = tid >> 2;
    const int kk  = (tid & 3) * 8;
    const int r16 = lane & 15;
    const int q   = lane >> 4;

    const float* A_base = enc + (size_t)m_block * 128 * D_DIM;
    const float* B_base = Wa + (size_t)n_block * 128 * WA_LD + D_DIM;

    floatx4 acc[4][4] = {};

    for (int k0 = 0; k0 < 1024; k0 += 32) {
        float4 a0l = *(const float4*)(A_base + (size_t)r0        * D_DIM + k0 + kk);
        float4 a0h = *(const float4*)(A_base + (size_t)r0        * D_DIM + k0 + kk + 4);
        float4 a1l = *(const float4*)(A_base + (size_t)(r0 + 64) * D_DIM + k0 + kk);
        float4 a1h = *(const float4*)(A_base + (size_t)(r0 + 64) * D_DIM + k0 + kk + 4);
        float4 b0l = *(const float4*)(B_base + (size_t)r0        * WA_LD + k0 + kk);
        float4 b0h = *(const float4*)(B_base + (size_t)r0        * WA_LD + k0 + kk + 4);
        float4 b1l = *(const float4*)(B_base + (size_t)(r0 + 64) * WA_LD + k0 + kk);
        float4 b1h = *(const float4*)(B_base + (size_t)(r0 + 64) * WA_LD + k0 + kk + 4);
        uint4 pa0 = { pack2(a0l.x, a0l.y), pack2(a0l.z, a0l.w), pack2(a0h.x, a0h.y), pack2(a0h.z, a0h.w) };
        uint4 pa1 = { pack2(a1l.x, a1l.y), pack2(a1l.z, a1l.w), pack2(a1h.x, a1h.y), pack2(a1h.z, a1h.w) };
        uint4 pb0 = { pack2(b0l.x, b0l.y), pack2(b0l.z, b0l.w), pack2(b0h.x, b0h.y), pack2(b0h.z, b0h.w) };
        uint4 pb1 = { pack2(b1l.x, b1l.y), pack2(b1l.z, b1l.w), pack2(b1h.x, b1h.y), pack2(b1h.z, b1h.w) };
        __syncthreads();
        *(uint4*)&As[r0        * 32 + kk] = pa0;
        *(uint4*)&As[(r0 + 64) * 32 + kk] = pa1;
        *(uint4*)&Bs[r0        * 32 + kk] = pb0;
        *(uint4*)&Bs[(r0 + 64) * 32 + kk] = pb1;
        __syncthreads();

        bf16x8 af[4], bfr[4];
        #pragma unroll
        for (int i = 0; i < 4; ++i)
            af[i] = *(const bf16x8*)&As[(wm * 64 + i * 16 + r16) * 32 + q * 8];
        #pragma unroll
        for (int j = 0; j < 4; ++j)
            bfr[j] = *(const bf16x8*)&Bs[(wn * 64 + j * 16 + r16) * 32 + q * 8];
        #pragma unroll
        for (int i = 0; i < 4; ++i)
            #pragma unroll
            for (int j = 0; j < 4; ++j)
                acc[i][j] = __builtin_amdgcn_mfma_f32_16x16x32_bf16(af[i], bfr[j], acc[i][j], 0, 0, 0);
    }

    float p[4][4] = {};
    #pragma unroll
    for (int j = 0; j < 4; ++j) {
        const int nl = wn * 64 + j * 16 + r16;
        const float dd = s_dec[nl];
        const float vv = s_v[nl];
        #pragma unroll
        for (int i = 0; i < 4; ++i) {
            #pragma unroll
            for (int r = 0; r < 4; ++r) {
                float x = acc[i][j][r] + dd;
                if (!(x > -8.f)) x = -8.f;
                if (x > 8.f)     x = 8.f;
                float e2 = __expf(2.f * x);
                float h  = 1.f - 2.f * __builtin_amdgcn_rcpf(e2 + 1.f);
                p[i][r] += h * vv;
            }
        }
    }
    #pragma unroll
    for (int msk = 1; msk < 16; msk <<= 1) {
        #pragma unroll
        for (int i = 0; i < 4; ++i)
            #pragma unroll
            for (int r = 0; r < 4; ++r)
                p[i][r] += __shfl_xor(p[i][r], msk, 64);
    }
    __syncthreads();
    if (wn == 0 && r16 == 0) {
        #pragma unroll
        for (int i = 0; i < 4; ++i)
            #pragma unroll
            for (int r = 0; r < 4; ++r)
                s_score[wm * 64 + i * 16 + q * 4 + r] = p[i][r];
    }
    __syncthreads();
    if (wn == 1 && r16 == 0) {
        #pragma unroll
        for (int i = 0; i < 4; ++i)
            #pragma unroll
            for (int r = 0; r < 4; ++r)
                s_score[wm * 64 + i * 16 + q * 4 + r] += p[i][r];
    }
    __syncthreads();
    if (tid < 128)
        partial[(size_t)n_block * M_TOT + m_block * 128 + tid] = s_score[tid];
}

// ---------------- kernel 3: softmax over s per batch row ----------------
__global__ __launch_bounds__(256) void softmax_kernel(
    const float* __restrict__ partial,   // [8][65536]
    float* __restrict__ out)             // [32][2048] f32
{
    const int b = blockIdx.x;
    const int tid = threadIdx.x;
    __shared__ float wmax[4], wsum[4];

    float sc[8];
    float mx = -1e30f;
    #pragma unroll
    for (int ii = 0; ii < 8; ++ii) {
        const int s = tid + ii * 256;
        float sum = 0.f;
        #pragma unroll
        for (int pp = 0; pp < 8; ++pp)
            sum += partial[(size_t)pp * M_TOT + b * S_DIM + s];
        sc[ii] = sum;
        mx = fmaxf(mx, sum);
    }
    #pragma unroll
    for (int msk = 1; msk < 64; msk <<= 1) mx = fmaxf(mx, __shfl_xor(mx, msk, 64));
    if ((tid & 63) == 0) wmax[tid >> 6] = mx;
    __syncthreads();
    mx = fmaxf(fmaxf(wmax[0], wmax[1]), fmaxf(wmax[2], wmax[3]));

    float ex[8];
    float tot = 0.f;
    #pragma unroll
    for (int ii = 0; ii < 8; ++ii) { ex[ii] = __expf(sc[ii] - mx); tot += ex[ii]; }
    #pragma unroll
    for (int msk = 1; msk < 64; msk <<= 1) tot += __shfl_xor(tot, msk, 64);
    if ((tid & 63) == 0) wsum[tid >> 6] = tot;
    __syncthreads();
    tot = wsum[0] + wsum[1] + wsum[2] + wsum[3];
    const float inv = 1.f / tot;
    #pragma unroll
    for (int ii = 0; ii < 8; ++ii)
        out[b * S_DIM + tid + ii * 256] = ex[ii] * inv;
}

extern "C" void kernel_launch(void* const* d_in, const int* in_sizes, int n_in,
                              void* d_out, int out_size, void* d_ws, size_t ws_size,
                              hipStream_t stream) {
    (void)in_sizes; (void)n_in; (void)out_size;
    const float* dec = (const float*)d_in[0];
    const float* enc = (const float*)d_in[1];
    const float* Wa  = (const float*)d_in[2];
    const float* v   = (const float*)d_in[3];
    float* out = (float*)d_out;

    float* dp      = (float*)d_ws;        // 32*1024 floats   = 128 KB
    float* partial = dp + 32 * 1024;      // 8*65536 floats   = 2 MB

    const size_t NEED = (size_t)(32 * 1024 + 8 * 65536) * 4
                      + (size_t)67108864 * 2            // enc bf16
                      + (size_t)1048576 * 2;            // We bf16

    if (ws_size >= NEED) {
        ushort_t* encb = (ushort_t*)(partial + 8 * 65536);
        ushort_t* Web  = encb + 67108864;
        convertW_kernel<<<dim3(1024), 256, 0, stream>>>(Wa, Web);
        convert_enc_kernel<<<dim3(4096), 256, 0, stream>>>(enc, encb);
        decproj_kernel<<<dim3(256, 32), 256, 0, stream>>>(dec, Wa, dp);
        gemm_bf16_kernel<<<dim3(8, 512), 256, 0, stream>>>(encb, Web, v, dp, partial);
    } else {
        decproj_kernel<<<dim3(256, 32), 256, 0, stream>>>(dec, Wa, dp);
        fused_gemm_fp32_kernel<<<dim3(8, 512), 256, 0, stream>>>(enc, Wa, v, dp, partial);
    }
    softmax_kernel<<<32, 256, 0, stream>>>(partial, out);
}